// Round 16
// baseline (47.823 us; speedup 1.0000x reference)
//
#include <hip/hip_runtime.h>
#include <hip/hip_bf16.h>

// MessagePassing: out[t] += x[s] for each edge (t, s), D=64.
// edge_index: [2, E] int32 (row 0 = targets, row 1 = sources), x: [N, 64] f32.
//
// Split pipeline: memset(brun) -> part (x->bf16 convert head + bucket
// partition) -> bsum (per-bucket counting sort in LDS + register accumulation
// over bf16 rows + spill tail).
// Round-16: part was running on 196 blocks (EPB=4096) -> 60 of 256 CUs idle
// through the whole partition+convert phase. Now EPB=2048/PTHR=512 -> 391
// blocks (~1.5/CU), per-block scan work halved, convert spread 2x wider.
// bsum unchanged (its levers all nulled: issue/byte/depth).

#define D 64
#define NB2 512         // coarse buckets
#define GPB_MAX 128     // max nodes/bucket (N <= 65536 for u16 packing)
#define CAP 2048        // pair words per bucket region
#define EPB 2048        // edges per part block
#define PTHR 512        // part threads
#define BTHR 1024       // bsum threads
#define SPILL_MAX 65536

__device__ __forceinline__ unsigned f2bf(float f) {
    unsigned u = __float_as_uint(f);
    return (u + 0x7FFFu + ((u >> 16) & 1u)) >> 16;   // RNE bf16
}
__device__ __forceinline__ float bf2f(unsigned short h) {
    return __uint_as_float(((unsigned)h) << 16);
}

// ---- 1: x->bf16 convert (head), then partition edges into fixed-cap bucket
//         regions (LDS-staged flush).  pair word = (local_tgt<<16)|src ----
__global__ __launch_bounds__(PTHR) void part_kernel(const int* __restrict__ tgt,
                                                    const int* __restrict__ src,
                                                    int* __restrict__ brun,
                                                    unsigned* __restrict__ pairs,
                                                    int* __restrict__ spill,
                                                    int* __restrict__ scnt,
                                                    const float* __restrict__ x,
                                                    unsigned* __restrict__ xbf,
                                                    int E, int N, int gpb) {
    __shared__ int h[NB2];
    __shared__ int coff[NB2];
    __shared__ int crun[NB2];
    __shared__ int gbase[NB2];
    __shared__ unsigned sw[EPB];
    __shared__ unsigned short sb[EPB];
    int t = threadIdx.x;
    int wid = t >> 6, lane = t & 63;
    int base = blockIdx.x * EPB;
    int nitems = E - base;
    if (nitems > EPB) nitems = EPB;
    if (nitems < 0) nitems = 0;

    // ---- head: convert x (N*64 f32) to bf16, 8 elems/thread/iter ----
    {
        const float4* xf4 = (const float4*)x;
        uint4* xb4 = (uint4*)xbf;
        int n8 = (N * D) >> 3;
        for (int i = blockIdx.x * PTHR + t; i < n8; i += gridDim.x * PTHR) {
            float4 a = xf4[2 * i], c = xf4[2 * i + 1];
            uint4 o;
            o.x = f2bf(a.x) | (f2bf(a.y) << 16);
            o.y = f2bf(a.z) | (f2bf(a.w) << 16);
            o.z = f2bf(c.x) | (f2bf(c.y) << 16);
            o.w = f2bf(c.z) | (f2bf(c.w) << 16);
            xb4[i] = o;
        }
    }

    for (int i = t; i < NB2; i += PTHR) h[i] = 0;
    __syncthreads();

    int myb[EPB / PTHR];
    unsigned myw[EPB / PTHR];
    #pragma unroll
    for (int k = 0; k < EPB / PTHR; ++k) {
        myb[k] = -1; myw[k] = 0;
        int j = t + k * PTHR;
        if (j < nitems) {
            int e = base + j;
            unsigned tg = (unsigned)tgt[e];
            unsigned s  = (unsigned)src[e];
            int bk = (int)(tg / (unsigned)gpb);
            myb[k] = bk;
            myw[k] = ((tg - (unsigned)bk * (unsigned)gpb) << 16) | s;
            atomicAdd(&h[bk], 1);
        }
    }
    __syncthreads();

    // wave-0 shfl scan of h[512] (8 entries/lane); gbase reservation by t<512
    if (wid == 0) {
        int b8 = lane * 8;
        int cvals[8], pre[8], s = 0;
        #pragma unroll
        for (int k = 0; k < 8; ++k) { cvals[k] = h[b8 + k]; pre[k] = s; s += cvals[k]; }
        int run = s;
        #pragma unroll
        for (int d2 = 1; d2 < 64; d2 <<= 1) {
            int v = __shfl_up(run, d2); if (lane >= d2) run += v;
        }
        int excl = run - s;
        #pragma unroll
        for (int k = 0; k < 8; ++k) {
            int v2 = excl + pre[k];
            coff[b8 + k] = v2;
            crun[b8 + k] = v2;
        }
    }
    if (t < NB2) {
        int hv = h[t];
        gbase[t] = hv ? atomicAdd(&brun[t], hv) : 0;   // brun zeroed by memset
    }
    __syncthreads();

    // place into staging (bucket-grouped within block)
    #pragma unroll
    for (int k = 0; k < EPB / PTHR; ++k) {
        if (myb[k] >= 0) {
            int pos = atomicAdd(&crun[myb[k]], 1);
            sw[pos] = myw[k];
            sb[pos] = (unsigned short)myb[k];
        }
    }
    __syncthreads();

    // flush: consecutive i within a bucket run -> consecutive global dst
    for (int i = t; i < nitems; i += PTHR) {
        int bk = sb[i];
        int dstl = gbase[bk] + (i - coff[bk]);     // count-relative offset
        if (dstl < CAP) {
            pairs[bk * CAP + dstl] = sw[i];
        } else {
            int sp2 = atomicAdd(scnt, 1);
            if (sp2 < SPILL_MAX) {
                unsigned w = sw[i];
                spill[2 * sp2]     = bk * gpb + (int)(w >> 16);
                spill[2 * sp2 + 1] = (int)(w & 0xffffu);
            }
        }
    }
}

// ---- 2: per-bucket counting sort (LDS) + register accumulate (bf16 rows) ----
// Wave wid owns nodes wid+16r (r<8, static). Lane = feature dim.
// 16 rows in flight per trip: deg~16 nodes finish in ONE memory round.
__global__ __launch_bounds__(BTHR) void bsum_kernel(const int* __restrict__ brun,
                                                    const unsigned* __restrict__ pairs,
                                                    const int* __restrict__ spill,
                                                    const int* __restrict__ scnt,
                                                    const unsigned short* __restrict__ xbf,
                                                    const float* __restrict__ x,
                                                    float* __restrict__ out,
                                                    int N, int gpb) {
    __shared__ unsigned sp[CAP];         // 8KB: staged pair words
    __shared__ unsigned short ss[CAP];   // 4KB: sorted src ids
    __shared__ int cnt2[GPB_MAX];
    __shared__ int roff[GPB_MAX + 1];
    __shared__ int wpos[GPB_MAX];
    int b = blockIdx.x;
    int t = threadIdx.x;
    int wid = t >> 6;
    int lane = t & 63;
    int lo = b * gpb;

    if (lo < N) {
        int hi = lo + gpb; if (hi > N) hi = N;
        int nn = hi - lo;
        int m = brun[b];
        if (m > CAP) m = CAP;       // excess went to the spill list

        // stage pair words (coalesced), zero counters
        for (int i = t; i < m; i += BTHR) sp[i] = pairs[b * CAP + i];
        if (t < GPB_MAX) cnt2[t] = 0;
        __syncthreads();
        // histogram of local targets (single-lane int atomics, from LDS)
        for (int i = t; i < m; i += BTHR) atomicAdd(&cnt2[sp[i] >> 16], 1);
        __syncthreads();
        // exclusive scan of 128 counters by wave 0 (shfl scan)
        if (wid == 0) {
            int c0 = cnt2[lane], c1 = cnt2[64 + lane];
            int s0c = c0, s1c = c1;
            #pragma unroll
            for (int d2 = 1; d2 < 64; d2 <<= 1) {
                int v = __shfl_up(s0c, d2); if (lane >= d2) s0c += v;
            }
            int tot0 = __shfl(s0c, 63);
            #pragma unroll
            for (int d2 = 1; d2 < 64; d2 <<= 1) {
                int v = __shfl_up(s1c, d2); if (lane >= d2) s1c += v;
            }
            roff[lane] = s0c - c0;        wpos[lane] = s0c - c0;
            roff[64 + lane] = tot0 + s1c - c1;
            wpos[64 + lane] = tot0 + s1c - c1;
            if (lane == 63) roff[GPB_MAX] = tot0 + s1c;
        }
        __syncthreads();
        // scatter src ids into sorted order (u16, LDS->LDS)
        for (int i = t; i < m; i += BTHR) {
            unsigned w = sp[i];
            int pos = atomicAdd(&wpos[w >> 16], 1);
            ss[pos] = (unsigned short)(w & 0xffffu);
        }
        __syncthreads();

        float acc[8];
        #pragma unroll
        for (int r = 0; r < 8; ++r) acc[r] = 0.f;
        // register accumulation; 16 bf16 rows (2KB) in flight per trip
        #pragma unroll
        for (int r = 0; r < 8; ++r) {
            int node = wid + (r << 4);           // wave-uniform
            if (node < nn) {
                int rs = roff[node], re = roff[node + 1];
                float a = acc[r];
                for (int j = rs; j < re; j += 16) {
                    int idv[16]; float vv[16];
                    #pragma unroll
                    for (int k = 0; k < 16; ++k) {
                        int jj = j + k;
                        idv[k] = ss[(jj < re) ? jj : rs];
                    }
                    #pragma unroll
                    for (int k = 0; k < 16; ++k)
                        vv[k] = bf2f(xbf[idv[k] * D + lane]);
                    #pragma unroll
                    for (int k = 0; k < 16; ++k)
                        if (j + k < re) a += vv[k];
                }
                acc[r] = a;
            }
        }
        // one coalesced store per node (zeros included)
        #pragma unroll
        for (int r = 0; r < 8; ++r) {
            int node = wid + (r << 4);
            if (node < nn) out[(size_t)(lo + node) * D + lane] = acc[r];
        }
    }

    // ---- spill tail: this bucket's overflow edges (normally zero) ----
    __syncthreads();
    int n = scnt[0]; if (n > SPILL_MAX) n = SPILL_MAX;
    if (n > 0) {
        for (int i = wid; i < n; i += 16) {
            int tg2 = spill[2 * i];
            if (tg2 / gpb == b) {
                int s2 = spill[2 * i + 1];
                atomicAdd(&out[(size_t)tg2 * D + lane], x[(size_t)s2 * D + lane]);
            }
        }
    }
}

// Fallback: direct atomic scatter-add.
__global__ void mp_scatter_add_kernel(const int* __restrict__ tgt,
                                      const int* __restrict__ src,
                                      const float* __restrict__ x,
                                      float* __restrict__ out,
                                      int E) {
    long long tid = (long long)blockIdx.x * blockDim.x + threadIdx.x;
    int e = (int)(tid >> 6);
    int d = (int)(tid & 63);
    if (e >= E) return;
    atomicAdd(&out[(long long)tgt[e] * D + d], x[(long long)src[e] * D + d]);
}

extern "C" void kernel_launch(void* const* d_in, const int* in_sizes, int n_in,
                              void* d_out, int out_size, void* d_ws, size_t ws_size,
                              hipStream_t stream) {
    const int* edge_index = (const int*)d_in[0];   // [2, E]
    const float* x        = (const float*)d_in[1]; // [N, 64]
    float* out            = (float*)d_out;         // [N, 64]

    int E = in_sizes[0] / 2;
    int N = out_size / D;
    const int* tgt = edge_index;       // edge_index[0]
    const int* src = edge_index + E;   // edge_index[1]

    int gpb = (N + NB2 - 1) / NB2;     // nodes per bucket (98 for N=50000)

    // ws layout (ints): brun[512] | scnt[4] | pairs[512*CAP] | spill[2*SPILL_MAX]
    //                   | xbf (N*64 bf16 = N*32 ints, 16B-aligned)
    size_t hdr = (size_t)(NB2 + 4 + (size_t)NB2 * CAP + 2 * SPILL_MAX);
    size_t need = (hdr + (size_t)N * (D / 2)) * sizeof(int);

    if (N > 65536 || gpb > GPB_MAX || ws_size < need) {
        hipMemsetAsync(d_out, 0, (size_t)out_size * sizeof(float), stream);
        long long total = (long long)E * D;
        long long grid = (total + 255) / 256;
        mp_scatter_add_kernel<<<(dim3)(unsigned)grid, 256, 0, stream>>>(tgt, src, x, out, E);
        return;
    }

    int* brun = (int*)d_ws;
    int* scnt = brun + NB2;
    unsigned* pairs = (unsigned*)(scnt + 4);
    int* spill = (int*)(pairs + (size_t)NB2 * CAP);
    unsigned* xbf = (unsigned*)(spill + 2 * SPILL_MAX);   // 16B-aligned

    // zero bucket cursors + spill count (counts are relative to b*CAP)
    hipMemsetAsync(brun, 0, (NB2 + 4) * sizeof(int), stream);

    int GE = (E + EPB - 1) / EPB;
    part_kernel<<<GE, PTHR, 0, stream>>>(tgt, src, brun, pairs, spill, scnt,
                                         x, xbf, E, N, gpb);
    bsum_kernel<<<NB2, BTHR, 0, stream>>>(brun, pairs, spill, scnt,
                                          (const unsigned short*)xbf, x, out, N, gpb);
}

// Round 17
// 44.371 us; speedup vs baseline: 1.0778x; 1.0778x over previous
//
#include <hip/hip_runtime.h>
#include <hip/hip_bf16.h>

// MessagePassing: out[t] += x[s] for each edge (t, s), D=64.
// edge_index: [2, E] int32 (row 0 = targets, row 1 = sources), x: [N, 64] f32.
//
// Split pipeline: memset(brun) -> part (x->bf16 convert head + bucket
// partition) -> bsum (per-bucket counting sort in LDS + register accumulation
// over bf16 rows + spill tail).
// Round-17: REVERT to round-15 config (EPB=4096/PTHR=1024, best: 44.5us).
// Round-16's EPB=2048/PTHR=512 split regressed (47.8us): per-block fixed
// work (512-counter scan, gbase atomics) doubled; part was never CU-starved.
// Lever ledger on this structure: VMEM-issue /4 null, bytes /2 -1.6us,
// depth x2 null, grid x2 regression -> structural floor.

#define D 64
#define NB2 512         // coarse buckets
#define GPB_MAX 128     // max nodes/bucket (N <= 65536 for u16 packing)
#define CAP 2048        // pair words per bucket region
#define EPB 4096        // edges per part block
#define PTHR 1024       // part threads
#define BTHR 1024       // bsum threads
#define SPILL_MAX 65536

__device__ __forceinline__ unsigned f2bf(float f) {
    unsigned u = __float_as_uint(f);
    return (u + 0x7FFFu + ((u >> 16) & 1u)) >> 16;   // RNE bf16
}
__device__ __forceinline__ float bf2f(unsigned short h) {
    return __uint_as_float(((unsigned)h) << 16);
}

// ---- 1: x->bf16 convert (head), then partition edges into fixed-cap bucket
//         regions (LDS-staged flush).  pair word = (local_tgt<<16)|src ----
__global__ __launch_bounds__(PTHR) void part_kernel(const int* __restrict__ tgt,
                                                    const int* __restrict__ src,
                                                    int* __restrict__ brun,
                                                    unsigned* __restrict__ pairs,
                                                    int* __restrict__ spill,
                                                    int* __restrict__ scnt,
                                                    const float* __restrict__ x,
                                                    unsigned* __restrict__ xbf,
                                                    int E, int N, int gpb) {
    __shared__ int h[NB2];
    __shared__ int coff[NB2];
    __shared__ int crun[NB2];
    __shared__ int gbase[NB2];
    __shared__ unsigned sw[EPB];
    __shared__ unsigned short sb[EPB];
    int t = threadIdx.x;
    int wid = t >> 6, lane = t & 63;
    int base = blockIdx.x * EPB;
    int nitems = E - base;
    if (nitems > EPB) nitems = EPB;
    if (nitems < 0) nitems = 0;

    // ---- head: convert x (N*64 f32) to bf16, 8 elems/thread/iter ----
    {
        const float4* xf4 = (const float4*)x;
        uint4* xb4 = (uint4*)xbf;
        int n8 = (N * D) >> 3;
        for (int i = blockIdx.x * PTHR + t; i < n8; i += gridDim.x * PTHR) {
            float4 a = xf4[2 * i], c = xf4[2 * i + 1];
            uint4 o;
            o.x = f2bf(a.x) | (f2bf(a.y) << 16);
            o.y = f2bf(a.z) | (f2bf(a.w) << 16);
            o.z = f2bf(c.x) | (f2bf(c.y) << 16);
            o.w = f2bf(c.z) | (f2bf(c.w) << 16);
            xb4[i] = o;
        }
    }

    for (int i = t; i < NB2; i += PTHR) h[i] = 0;
    __syncthreads();

    int myb[EPB / PTHR];
    unsigned myw[EPB / PTHR];
    #pragma unroll
    for (int k = 0; k < EPB / PTHR; ++k) {
        myb[k] = -1; myw[k] = 0;
        int j = t + k * PTHR;
        if (j < nitems) {
            int e = base + j;
            unsigned tg = (unsigned)tgt[e];
            unsigned s  = (unsigned)src[e];
            int bk = (int)(tg / (unsigned)gpb);
            myb[k] = bk;
            myw[k] = ((tg - (unsigned)bk * (unsigned)gpb) << 16) | s;
            atomicAdd(&h[bk], 1);
        }
    }
    __syncthreads();

    // wave-0 shfl scan of h[512] (8 entries/lane); gbase reservation by t<512
    if (wid == 0) {
        int b8 = lane * 8;
        int cvals[8], pre[8], s = 0;
        #pragma unroll
        for (int k = 0; k < 8; ++k) { cvals[k] = h[b8 + k]; pre[k] = s; s += cvals[k]; }
        int run = s;
        #pragma unroll
        for (int d2 = 1; d2 < 64; d2 <<= 1) {
            int v = __shfl_up(run, d2); if (lane >= d2) run += v;
        }
        int excl = run - s;
        #pragma unroll
        for (int k = 0; k < 8; ++k) {
            int v2 = excl + pre[k];
            coff[b8 + k] = v2;
            crun[b8 + k] = v2;
        }
    }
    if (t < NB2) {
        int hv = h[t];
        gbase[t] = hv ? atomicAdd(&brun[t], hv) : 0;   // brun zeroed by memset
    }
    __syncthreads();

    // place into staging (bucket-grouped within block)
    #pragma unroll
    for (int k = 0; k < EPB / PTHR; ++k) {
        if (myb[k] >= 0) {
            int pos = atomicAdd(&crun[myb[k]], 1);
            sw[pos] = myw[k];
            sb[pos] = (unsigned short)myb[k];
        }
    }
    __syncthreads();

    // flush: consecutive i within a bucket run -> consecutive global dst
    for (int i = t; i < nitems; i += PTHR) {
        int bk = sb[i];
        int dstl = gbase[bk] + (i - coff[bk]);     // count-relative offset
        if (dstl < CAP) {
            pairs[bk * CAP + dstl] = sw[i];
        } else {
            int sp2 = atomicAdd(scnt, 1);
            if (sp2 < SPILL_MAX) {
                unsigned w = sw[i];
                spill[2 * sp2]     = bk * gpb + (int)(w >> 16);
                spill[2 * sp2 + 1] = (int)(w & 0xffffu);
            }
        }
    }
}

// ---- 2: per-bucket counting sort (LDS) + register accumulate (bf16 rows) ----
// Wave wid owns nodes wid+16r (r<8, static). Lane = feature dim.
// 16 rows in flight per trip: deg~16 nodes finish in ONE memory round.
__global__ __launch_bounds__(BTHR) void bsum_kernel(const int* __restrict__ brun,
                                                    const unsigned* __restrict__ pairs,
                                                    const int* __restrict__ spill,
                                                    const int* __restrict__ scnt,
                                                    const unsigned short* __restrict__ xbf,
                                                    const float* __restrict__ x,
                                                    float* __restrict__ out,
                                                    int N, int gpb) {
    __shared__ unsigned sp[CAP];         // 8KB: staged pair words
    __shared__ unsigned short ss[CAP];   // 4KB: sorted src ids
    __shared__ int cnt2[GPB_MAX];
    __shared__ int roff[GPB_MAX + 1];
    __shared__ int wpos[GPB_MAX];
    int b = blockIdx.x;
    int t = threadIdx.x;
    int wid = t >> 6;
    int lane = t & 63;
    int lo = b * gpb;

    if (lo < N) {
        int hi = lo + gpb; if (hi > N) hi = N;
        int nn = hi - lo;
        int m = brun[b];
        if (m > CAP) m = CAP;       // excess went to the spill list

        // stage pair words (coalesced), zero counters
        for (int i = t; i < m; i += BTHR) sp[i] = pairs[b * CAP + i];
        if (t < GPB_MAX) cnt2[t] = 0;
        __syncthreads();
        // histogram of local targets (single-lane int atomics, from LDS)
        for (int i = t; i < m; i += BTHR) atomicAdd(&cnt2[sp[i] >> 16], 1);
        __syncthreads();
        // exclusive scan of 128 counters by wave 0 (shfl scan)
        if (wid == 0) {
            int c0 = cnt2[lane], c1 = cnt2[64 + lane];
            int s0c = c0, s1c = c1;
            #pragma unroll
            for (int d2 = 1; d2 < 64; d2 <<= 1) {
                int v = __shfl_up(s0c, d2); if (lane >= d2) s0c += v;
            }
            int tot0 = __shfl(s0c, 63);
            #pragma unroll
            for (int d2 = 1; d2 < 64; d2 <<= 1) {
                int v = __shfl_up(s1c, d2); if (lane >= d2) s1c += v;
            }
            roff[lane] = s0c - c0;        wpos[lane] = s0c - c0;
            roff[64 + lane] = tot0 + s1c - c1;
            wpos[64 + lane] = tot0 + s1c - c1;
            if (lane == 63) roff[GPB_MAX] = tot0 + s1c;
        }
        __syncthreads();
        // scatter src ids into sorted order (u16, LDS->LDS)
        for (int i = t; i < m; i += BTHR) {
            unsigned w = sp[i];
            int pos = atomicAdd(&wpos[w >> 16], 1);
            ss[pos] = (unsigned short)(w & 0xffffu);
        }
        __syncthreads();

        float acc[8];
        #pragma unroll
        for (int r = 0; r < 8; ++r) acc[r] = 0.f;
        // register accumulation; 16 bf16 rows (2KB) in flight per trip
        #pragma unroll
        for (int r = 0; r < 8; ++r) {
            int node = wid + (r << 4);           // wave-uniform
            if (node < nn) {
                int rs = roff[node], re = roff[node + 1];
                float a = acc[r];
                for (int j = rs; j < re; j += 16) {
                    int idv[16]; float vv[16];
                    #pragma unroll
                    for (int k = 0; k < 16; ++k) {
                        int jj = j + k;
                        idv[k] = ss[(jj < re) ? jj : rs];
                    }
                    #pragma unroll
                    for (int k = 0; k < 16; ++k)
                        vv[k] = bf2f(xbf[idv[k] * D + lane]);
                    #pragma unroll
                    for (int k = 0; k < 16; ++k)
                        if (j + k < re) a += vv[k];
                }
                acc[r] = a;
            }
        }
        // one coalesced store per node (zeros included)
        #pragma unroll
        for (int r = 0; r < 8; ++r) {
            int node = wid + (r << 4);
            if (node < nn) out[(size_t)(lo + node) * D + lane] = acc[r];
        }
    }

    // ---- spill tail: this bucket's overflow edges (normally zero) ----
    __syncthreads();
    int n = scnt[0]; if (n > SPILL_MAX) n = SPILL_MAX;
    if (n > 0) {
        for (int i = wid; i < n; i += 16) {
            int tg2 = spill[2 * i];
            if (tg2 / gpb == b) {
                int s2 = spill[2 * i + 1];
                atomicAdd(&out[(size_t)tg2 * D + lane], x[(size_t)s2 * D + lane]);
            }
        }
    }
}

// Fallback: direct atomic scatter-add.
__global__ void mp_scatter_add_kernel(const int* __restrict__ tgt,
                                      const int* __restrict__ src,
                                      const float* __restrict__ x,
                                      float* __restrict__ out,
                                      int E) {
    long long tid = (long long)blockIdx.x * blockDim.x + threadIdx.x;
    int e = (int)(tid >> 6);
    int d = (int)(tid & 63);
    if (e >= E) return;
    atomicAdd(&out[(long long)tgt[e] * D + d], x[(long long)src[e] * D + d]);
}

extern "C" void kernel_launch(void* const* d_in, const int* in_sizes, int n_in,
                              void* d_out, int out_size, void* d_ws, size_t ws_size,
                              hipStream_t stream) {
    const int* edge_index = (const int*)d_in[0];   // [2, E]
    const float* x        = (const float*)d_in[1]; // [N, 64]
    float* out            = (float*)d_out;         // [N, 64]

    int E = in_sizes[0] / 2;
    int N = out_size / D;
    const int* tgt = edge_index;       // edge_index[0]
    const int* src = edge_index + E;   // edge_index[1]

    int gpb = (N + NB2 - 1) / NB2;     // nodes per bucket (98 for N=50000)

    // ws layout (ints): brun[512] | scnt[4] | pairs[512*CAP] | spill[2*SPILL_MAX]
    //                   | xbf (N*64 bf16 = N*32 ints, 16B-aligned)
    size_t hdr = (size_t)(NB2 + 4 + (size_t)NB2 * CAP + 2 * SPILL_MAX);
    size_t need = (hdr + (size_t)N * (D / 2)) * sizeof(int);

    if (N > 65536 || gpb > GPB_MAX || ws_size < need) {
        hipMemsetAsync(d_out, 0, (size_t)out_size * sizeof(float), stream);
        long long total = (long long)E * D;
        long long grid = (total + 255) / 256;
        mp_scatter_add_kernel<<<(dim3)(unsigned)grid, 256, 0, stream>>>(tgt, src, x, out, E);
        return;
    }

    int* brun = (int*)d_ws;
    int* scnt = brun + NB2;
    unsigned* pairs = (unsigned*)(scnt + 4);
    int* spill = (int*)(pairs + (size_t)NB2 * CAP);
    unsigned* xbf = (unsigned*)(spill + 2 * SPILL_MAX);   // 16B-aligned

    // zero bucket cursors + spill count (counts are relative to b*CAP)
    hipMemsetAsync(brun, 0, (NB2 + 4) * sizeof(int), stream);

    int GE = (E + EPB - 1) / EPB;
    part_kernel<<<GE, PTHR, 0, stream>>>(tgt, src, brun, pairs, spill, scnt,
                                         x, xbf, E, N, gpb);
    bsum_kernel<<<NB2, BTHR, 0, stream>>>(brun, pairs, spill, scnt,
                                          (const unsigned short*)xbf, x, out, N, gpb);
}